// Round 9
// baseline (662.568 us; speedup 1.0000x reference)
//
#include <hip/hip_runtime.h>

// SpectralMapDecomposition, fully fused single kernel.
//   sep[b,i,h,w] = (1/256)*( ReC[b,h,i]*cos(2*pi*i*w/256) - ImC[b,h,i]*sin(2*pi*i*w/256) )
//   C[b,h,i] = sum_x img[b,h,x] * exp(-2*pi*j*i*x/256)
//   out = concat([sep (256 ch), mask (32 ch)], axis=1) -> (8, 288, 256, 256) fp32
//
// R7 post-mortem: full fusion was NEUTRAL (650.8 -> 649.8) just like the dft rewrite
// (651.6 -> 650.8). Three structures, same time => the invariant is the pole. The one
// thing all three share: ALL output bytes written via __builtin_nontemporal_store.
// Effective write BW ours ~2.5 TB/s vs the plain-store fill's 6.29 TB/s on the SAME
// buffer. Theory: gfx950 nt (no-allocate) stores bypass L2 write-coalescing and cap
// streaming writes; plain stores are the fill-proven fast path.
//
// R8 change (single variable): nt stores -> plain stores. Everything else identical.
// Predict: dur 650 -> ~490-530 if right; unchanged if wrong (then the pole is in the
// timing window, not the kernel).
// R9: resubmit (GPU acquisition timeout; R8 experiment never measured).

#define TWO_PI_OVER_256 0.02454369260617026f
#define SR 260   // padded LDS row stride in floats: dft read banks -> uniform 2-way (free)

typedef float vfloat4 __attribute__((ext_vector_type(4)));

__global__ __launch_bounds__(256) void fused_kernel(const float* __restrict__ img,
                                                    const vfloat4* __restrict__ mask,
                                                    float* __restrict__ out) {
    const int t   = threadIdx.x;
    const int blk = blockIdx.x;

    if (blk >= 2048) {
        // ---- mask copy: 67MB, 2048 blocks x 256 threads x 8 float4 ----
        const int mb = blk - 2048;
#pragma unroll
        for (int k = 0; k < 8; ++k) {
            const size_t e = (size_t)mb * 256 + t + (size_t)k * 524288;  // 0..4194303
            const size_t b = e >> 19;                                    // 524288 f4/batch
            const size_t r = e & 524287;
            const vfloat4 v = __builtin_nontemporal_load(&mask[b * 524288 + r]);
            ((vfloat4*)out)[b * 4718592 + 4194304 + r] = v;              // plain store
        }
        return;
    }

    // ---- fused dft+expand: block owns output channel (b, i) ----
    __shared__ float  rows[32 * SR];   // 32 img rows, padded stride
    __shared__ float2 cp[32];          // C[b, h0..h0+31, i], pre-scaled by 1/256
    const int b = blk >> 8;
    const int i = blk & 255;

    // dft lanes: xc = x-phase (0..7), hl = row within tile (0..31); x = xc + 8*x2
    const int xc = t & 7;
    const int hl = t >> 3;
    float c0, s0, cst, sst;
    __sincosf((float)((i * xc) & 255) * TWO_PI_OVER_256, &s0, &c0);   // phasor start
    __sincosf((float)((i * 8)  & 255) * TWO_PI_OVER_256, &sst, &cst); // step e^{j*2pi*8i/256}

    // expand lanes: thread owns 4 consecutive w for 1-of-4 h rows per iteration
    const int wb  = (t & 63) * 4;
    const int hl2 = t >> 6;
    float cw[4], sw[4];
#pragma unroll
    for (int j = 0; j < 4; ++j) {
        const int k = (i * (wb + j)) & 255;    // exact twiddle index
        __sincosf((float)k * TWO_PI_OVER_256, &sw[j], &cw[j]);
    }

    const float* __restrict__ imgb  = img + (size_t)b * 65536;
    float* __restrict__       obase = out + ((size_t)b * 288 + i) * 65536;

    for (int tile = 0; tile < 8; ++tile) {
        const int h0 = tile * 32;
        // stage 32 rows (32KB) as float2; reads are L2-hits after first touch
        const float2* __restrict__ src = (const float2*)(imgb + h0 * 256);
#pragma unroll
        for (int j = 0; j < 8; ++j) {
            const int idx = t + j * 256;               // 0..2047 (float2 pairs x2)
            const int rr  = idx >> 7;                  // row 0..15  (128 f2/row)
            const int c2  = idx & 127;
            *(float2*)&rows[rr * SR + 2 * c2]        = src[rr * 128 + c2];
            *(float2*)&rows[(rr + 16) * SR + 2 * c2] = src[(rr + 16) * 128 + c2];
        }
        __syncthreads();

        // per-thread partial DFT over x = xc + 8*x2 (in-register phasor, drift ~4e-6)
        float re = 0.f, im = 0.f, c = c0, s = s0;
        const float* __restrict__ rp = &rows[hl * SR + xc];
#pragma unroll
        for (int x2 = 0; x2 < 32; ++x2) {
            const float rv = rp[8 * x2];               // 2-way banked -> free
            re = fmaf(rv, c, re);
            im = fmaf(rv, s, im);                      // +sum(r*sin); negated at cp write
            const float cn = fmaf(c, cst, -s * sst);
            s = fmaf(s, cst, c * sst);
            c = cn;
        }
        // reduce the 8 x-phases (adjacent lanes) -> full C[h0+hl]
        re += __shfl_xor(re, 1); im += __shfl_xor(im, 1);
        re += __shfl_xor(re, 2); im += __shfl_xor(im, 2);
        re += __shfl_xor(re, 4); im += __shfl_xor(im, 4);
        if (xc == 0) cp[hl] = make_float2(re * (1.f / 256.f), im * (-1.f / 256.f));
        __syncthreads();

        // expand these 32 rows: 8 iters x 4KB contiguous plain stores
#pragma unroll
        for (int it2 = 0; it2 < 8; ++it2) {
            const int h = it2 * 4 + hl2;
            const float2 cv = cp[h];                   // wave-uniform -> LDS broadcast
            vfloat4 v;
            v.x = cv.x * cw[0] - cv.y * sw[0];
            v.y = cv.x * cw[1] - cv.y * sw[1];
            v.z = cv.x * cw[2] - cv.y * sw[2];
            v.w = cv.x * cw[3] - cv.y * sw[3];
            *reinterpret_cast<vfloat4*>(obase + (size_t)(h0 + h) * 256 + wb) = v;  // plain
        }
        // rows rewrite next tile is safe: all dft reads completed before the 2nd sync;
        // cp rewrite next tile is safe: expand reads complete before next tile's 1st sync.
    }
}

extern "C" void kernel_launch(void* const* d_in, const int* in_sizes, int n_in,
                              void* d_out, int out_size, void* d_ws, size_t ws_size,
                              hipStream_t stream) {
    const float* img  = (const float*)d_in[0];   // (8,1,256,256) fp32
    const float* mask = (const float*)d_in[1];   // (8,32,256,256) fp32
    float* out = (float*)d_out;                  // (8,288,256,256) fp32

    fused_kernel<<<4096, 256, 0, stream>>>(img, (const vfloat4*)mask, out);
}